// Round 2
// baseline (119.003 us; speedup 1.0000x reference)
//
#include <hip/hip_runtime.h>

// ---------------- problem constants ----------------
#define B_N  32
#define CI   128
#define CO   256
#define HH   64
#define WW   64
#define HP   66          // padded height
#define WP   66          // padded width
#define KTOT 1152        // 9 taps * 128 ci
#define PIX  4096        // 64*64

#define XT_ELEMS ((size_t)B_N * HP * WP * CI)
#define XT_BYTES (XT_ELEMS * 2)                 // 35,684,352 B
#define WT_ELEMS ((size_t)CO * KTOT)
#define WT_BYTES (WT_ELEMS * 2)
#define WS_NEEDED (XT_BYTES + WT_BYTES)

#define AS1 __attribute__((address_space(1)))
#define AS3 __attribute__((address_space(3)))

typedef unsigned short us;
typedef __attribute__((ext_vector_type(8))) short bf16x8;
typedef __attribute__((ext_vector_type(4))) float f32x4;
typedef __attribute__((ext_vector_type(8))) unsigned short us8;

__device__ __forceinline__ us f2bf(float f) {
    unsigned int u = __builtin_bit_cast(unsigned int, f);
    u += 0x7fffu + ((u >> 16) & 1u);   // RNE
    return (us)(u >> 16);
}

__device__ __forceinline__ void gload16(const void* g, const void* l) {
    __builtin_amdgcn_global_load_lds((const AS1 unsigned int*)g,
                                     (AS3 unsigned int*)l, 16, 0, 0);
}

// ---------------- prologue 1: NCHW fp32 -> padded NHWC bf16 (+borders) ------
__global__ void k_transpose(const float* __restrict__ X, us* __restrict__ Xt) {
    int bh   = blockIdx.x;
    int b    = bh >> 6, h = bh & 63;
    int wv   = threadIdx.x >> 6;
    int lane = threadIdx.x & 63;     // w
    const float* src = X + (((size_t)(b * CI + wv * 32) * HH + h) << 6) + lane;
    us8 v[4];
#pragma unroll
    for (int j = 0; j < 32; ++j)
        v[j >> 3][j & 7] = f2bf(src[(size_t)j << 12]);
    us* dst = Xt + ((size_t)(b * HP + h + 1) * WP + (lane + 1)) * CI + wv * 32;
#pragma unroll
    for (int q = 0; q < 4; ++q)
        *(us8*)(dst + q * 8) = v[q];
    // ---- border zeroing (replaces the 35.7MB memset) ----
    us8 z = (us8)0;
    int t = threadIdx.x;
    if (t < 32) {                          // cols 0 and 65 of padded row h+1
        int wcol = (t < 16) ? 0 : 65;
        int i = t & 15;
        *(us8*)(Xt + ((size_t)(b * HP + h + 1) * WP + wcol) * CI + i * 8) = z;
    }
    if (h == 0) {                          // padded row 0
        for (int i = t; i < WP * CI / 8; i += 256)
            *(us8*)(Xt + (size_t)(b * HP + 0) * WP * CI + (size_t)i * 8) = z;
    }
    if (h == 63) {                         // padded row 65
        for (int i = t; i < WP * CI / 8; i += 256)
            *(us8*)(Xt + (size_t)(b * HP + 65) * WP * CI + (size_t)i * 8) = z;
    }
}

// ---------------- prologue 2: weights -> Wt[co][k], k = tap*128 + ci --------
__global__ void k_prepw(const float* __restrict__ W, us* __restrict__ Wt) {
    int co = blockIdx.x;
    for (int k = threadIdx.x; k < KTOT; k += 256) {
        int tap = k >> 7, ci = k & 127;
        Wt[(size_t)co * KTOT + k] = f2bf(W[((size_t)co * CI + ci) * 9 + tap]);
    }
}

// ---------------- main: 256x256 tile, BK=64, 8 waves, phase-split + counted vmcnt
__global__ __launch_bounds__(512, 2) void k_conv_gemm(
    const us* __restrict__ Xt, const us* __restrict__ Wt,
    const float* __restrict__ bias, float* __restrict__ out) {

    // 2 slots each: A = [256 co][64 k], B = [256 row-permuted pix][64 k]; 128 KiB
    __shared__ __attribute__((aligned(16))) us As[2][256 * 64];
    __shared__ __attribute__((aligned(16))) us Bs[2][256 * 64];

    // bijective XCD swizzle (512 = 8 * 64)
    const int bid0 = blockIdx.x;
    const int bid  = (bid0 & 7) * 64 + (bid0 >> 3);
    const int b    = bid >> 4;
    const int nb   = bid & 15;
    const int h0   = nb << 2;            // 4 image rows per block

    const int tid  = threadIdx.x;
    const int lane = tid & 63;
    const int wv   = tid >> 6;
    const int lr   = lane & 15, lg = lane >> 4;
    const int wm   = wv >> 2,  wn = wv & 3;

    // staging map: per gload issue, thread covers row chunkbase+srow, group sg
    const int srow = tid >> 3;                 // 0..63
    const int sg   = (tid & 7) ^ (srow & 7);   // inverse-swizzled source group

    f32x4 acc[8][4] = {};                      // [mfrag][nfrag]

    // A staging: regions qm -> rows {qm*64..+63, 128+qm*64..+63}
    auto stageA = [&](int slot, int t, int qm) {
#pragma unroll
        for (int c = 0; c < 2; ++c) {
            const int r0 = qm * 64 + c * 128;
            const us* src = Wt + (size_t)(r0 + srow) * KTOT + t * 64 + sg * 8;
            const us* d   = &As[slot][(r0 + (wv << 3)) * 64];   // wave-uniform
            gload16(src, d);
        }
    };
    // B staging: LDS rows permuted so qn-half is contiguous:
    //   LDS row r -> pixel p = ((r>>5)&3)*64 + (r>>7)*32 + (r&31)
    auto stageB = [&](int slot, int t, int qn) {
        const int tap = t >> 1, ci0 = (t & 1) << 6;
        const int kh = tap / 3, kw = tap - kh * 3;
#pragma unroll
        for (int c = 0; c < 2; ++c) {
            const int r  = qn * 128 + c * 64 + srow;
            const int p  = ((r >> 5) & 3) * 64 + (r >> 7) * 32 + (r & 31);
            const int hh = h0 + (p >> 6) + kh;
            const int wc = (p & 63) + kw;
            const us* src = Xt + ((size_t)(b * HP + hh) * WP + wc) * CI + ci0 + sg * 8;
            const us* d   = &Bs[slot][(qn * 128 + c * 64 + (wv << 3)) * 64];
            gload16(src, d);
        }
    };

    bf16x8 a[4][2], bb[2][2];
    auto ldA = [&](int slot, int qm) {
#pragma unroll
        for (int m = 0; m < 4; ++m)
#pragma unroll
            for (int kk = 0; kk < 2; ++kk) {
                const int row = wm * 128 + qm * 64 + m * 16 + lr;
                const int g   = (kk * 4 + lg) ^ (row & 7);
                a[m][kk] = *(const bf16x8*)&As[slot][row * 64 + g * 8];
            }
    };
    auto ldB = [&](int slot, int qn) {
#pragma unroll
        for (int n = 0; n < 2; ++n)
#pragma unroll
            for (int kk = 0; kk < 2; ++kk) {
                const int r = qn * 128 + wn * 32 + n * 16 + lr;
                const int g = (kk * 4 + lg) ^ (r & 7);
                bb[n][kk] = *(const bf16x8*)&Bs[slot][r * 64 + g * 8];
            }
    };
    auto mma = [&](int qm, int qn) {
        __builtin_amdgcn_s_setprio(1);
#pragma unroll
        for (int kk = 0; kk < 2; ++kk)
#pragma unroll
            for (int m = 0; m < 4; ++m)
#pragma unroll
                for (int n = 0; n < 2; ++n)
                    acc[qm * 4 + m][qn * 2 + n] = __builtin_amdgcn_mfma_f32_16x16x32_bf16(
                        a[m][kk], bb[n][kk], acc[qm * 4 + m][qn * 2 + n], 0, 0, 0);
        __builtin_amdgcn_s_setprio(0);
    };

    // prologue: stage tile 0 into slot 0 (issue order I0..I3)
    stageA(0, 0, 0);   // I0: A-even
    stageB(0, 0, 0);   // I1: B-even
    stageA(0, 0, 1);   // I2: A-odd
    stageB(0, 0, 1);   // I3: B-odd

    for (int t = 0; t < 18; ++t) {
        const int s = t & 1, ns = s ^ 1;
        const int tn = (t < 17) ? t + 1 : 17;   // tail: redundant re-stage, keeps counts uniform
        // P1 (qm0,qn0): needs A-even,B-even of tile t landed
        asm volatile("s_waitcnt vmcnt(4)" ::: "memory");
        __builtin_amdgcn_s_barrier();
        stageA(ns, tn, 0);
        ldA(s, 0); ldB(s, 0);
        mma(0, 0);
        // P2 (qm1,qn0): needs A-odd
        asm volatile("s_waitcnt vmcnt(4)" ::: "memory");
        __builtin_amdgcn_s_barrier();
        stageB(ns, tn, 0);
        ldA(s, 1);
        mma(1, 0);
        // P3 (qm1,qn1): needs B-odd
        asm volatile("s_waitcnt vmcnt(4)" ::: "memory");
        __builtin_amdgcn_s_barrier();
        stageA(ns, tn, 1);
        ldB(s, 1);
        mma(1, 1);
        // P4 (qm0,qn1): everything already landed; no wait, no barrier
        stageB(ns, tn, 1);
        ldA(s, 0);
        mma(0, 1);
    }

    // epilogue: C/D frag col = lane&15, row = (lane>>4)*4 + j
    const int p0base = nb * 256 + wn * 64;
#pragma unroll
    for (int mf = 0; mf < 8; ++mf) {
        const int qm = mf >> 2, m = mf & 3;
#pragma unroll
        for (int j = 0; j < 4; ++j) {
            const int co = wm * 128 + qm * 64 + m * 16 + lg * 4 + j;
            const float bv = bias[co];
            float* op = out + ((size_t)(b * CO + co) << 12) + p0base + lr;
#pragma unroll
            for (int nf = 0; nf < 4; ++nf) {
                const int qn = nf >> 1, n = nf & 1;
                op[qn * 32 + n * 16] = acc[mf][nf][j] + bv;
            }
        }
    }
}

// ---------------- fallback: direct fp32 conv ----------------
__global__ void k_naive(const float* __restrict__ X, const float* __restrict__ W,
                        const float* __restrict__ bias, float* __restrict__ out) {
    long idx = (long)blockIdx.x * blockDim.x + threadIdx.x;
    if (idx >= (long)B_N * CO * PIX) return;
    int p = idx & 4095, co = (int)((idx >> 12) & 255), b = (int)(idx >> 20);
    int h = p >> 6, w = p & 63;
    float s = bias[co];
    for (int ci = 0; ci < CI; ++ci) {
        const float* xp = X + ((size_t)(b * CI + ci) << 12);
        const float* wp = W + ((size_t)(co * CI + ci)) * 9;
        for (int kh = 0; kh < 3; ++kh) {
            int hh2 = h + kh - 1; if ((unsigned)hh2 >= 64u) continue;
            for (int kw = 0; kw < 3; ++kw) {
                int ww2 = w + kw - 1; if ((unsigned)ww2 >= 64u) continue;
                s += xp[(hh2 << 6) + ww2] * wp[kh * 3 + kw];
            }
        }
    }
    out[idx] = s;
}

extern "C" void kernel_launch(void* const* d_in, const int* in_sizes, int n_in,
                              void* d_out, int out_size, void* d_ws, size_t ws_size,
                              hipStream_t stream) {
    const float* X    = (const float*)d_in[0];
    const float* W    = (const float*)d_in[1];
    const float* bias = (const float*)d_in[2];
    float* out = (float*)d_out;

    if (ws_size < WS_NEEDED) {
        long total = (long)B_N * CO * PIX;
        k_naive<<<(int)((total + 255) / 256), 256, 0, stream>>>(X, W, bias, out);
        return;
    }

    us* Xt = (us*)d_ws;
    us* Wt = (us*)((char*)d_ws + XT_BYTES);

    k_transpose<<<B_N * HH, 256, 0, stream>>>(X, Xt);
    k_prepw<<<CO, 256, 0, stream>>>(W, Wt);
    k_conv_gemm<<<512, 512, 0, stream>>>(Xt, Wt, bias, out);
}